// Round 13
// baseline (3875.271 us; speedup 1.0000x reference)
//
#include <hip/hip_runtime.h>

#define B_ 128
#define T_ 256
#define IN_ 128
#define G_ 5
#define H_ 512
#define G3_ 1536
#define E_ 1024
#define L_ 256
#define LG_ 251
#define INPG_ 133

#define MU_OFF (B_*T_*IN_)            /* 4194304 */
#define LV_OFF (MU_OFF + B_*LG_)      /* 4226432 */

#define DRS 524   /* notes_mfma LDS row stride; 262 dw = 6 mod 32 */

typedef __attribute__((ext_vector_type(8))) short bf16x8;
typedef __attribute__((ext_vector_type(4))) float f32x4;
typedef unsigned long long u64;

__device__ __forceinline__ float bf2f(unsigned short s) {
    return __uint_as_float(((unsigned)s) << 16);
}
__device__ __forceinline__ unsigned short f2bf(float f) {
    unsigned x = __float_as_uint(f);
    unsigned r = (x + 0x7fffu + ((x >> 16) & 1u)) >> 16;
    return (unsigned short)r;
}
__device__ __forceinline__ float sigf(float v) {
    return __builtin_amdgcn_rcpf(1.f + __expf(-v));
}
__device__ __forceinline__ float ftanh(float x) {
    x = fminf(15.f, fmaxf(-15.f, x));
    float e = __expf(2.f * x);
    return (e - 1.f) * __builtin_amdgcn_rcpf(e + 1.f);
}
// ---- agent-scope (cross-XCD coherent) ops ----
__device__ __forceinline__ u64 ld_h64(const void* p) {
    return __hip_atomic_load((const u64*)p, __ATOMIC_RELAXED, __HIP_MEMORY_SCOPE_AGENT);
}
__device__ __forceinline__ void st_h16(ushort* p, ushort v) {
    __hip_atomic_store(p, v, __ATOMIC_RELAXED, __HIP_MEMORY_SCOPE_AGENT);
}
// nonzero iff some 16-bit lane of v equals 0xFFFF (bf16 NaN poison)
__device__ __forceinline__ u64 badm(u64 v) {
    u64 x = ~v;
    return (x - 0x0001000100010001ull) & ~x & 0x8000800080008000ull;
}
__device__ __forceinline__ bf16x8 mk_frag(u64 lo, u64 hi) {
    bf16x8 a;
    ((u64*)&a)[0] = lo; ((u64*)&a)[1] = hi;
    return a;
}
__device__ __forceinline__ bf16x8 lds_frag(const ushort* p) {
    u64 lo = *(const u64*)p;
    u64 hi = *(const u64*)(p + 4);
    return mk_frag(lo, hi);
}

// =============== prep kernels ===============

__global__ void xpad_k(const float* __restrict__ x, ushort* __restrict__ xb) {
    int id = blockIdx.x * 256 + threadIdx.x;
    if (id >= T_ * B_ * 160) return;
    int t = id / (B_ * 160);
    int rem = id - t * (B_ * 160);
    int b = rem / 160, c = rem - b * 160;
    float v = (c < INPG_) ? x[((size_t)b * T_ + t) * INPG_ + c] : 0.f;
    xb[id] = f2bf(v);
}

// encoder weight pack: WE chunks [(dir*32+cb)*63 + ks][64 lanes][8 bf16]
// planes: ks 0..20 r(cat672), 21..41 z(cat672), 42..46 nx(K160), 47..62 nh(K512)
__global__ void pack_we(const float* __restrict__ Wih_f, const float* __restrict__ Whh_f,
                        const float* __restrict__ Wih_b, const float* __restrict__ Whh_b,
                        ushort* __restrict__ WE) {
    int id = blockIdx.x * 256 + threadIdx.x;
    int lane = id & 63;
    int rest = id >> 6;
    int ks = rest % 63;
    int cb = (rest / 63) & 31;
    int dir = rest / (63 * 32);
    if (dir >= 2) return;
    const float* Wih = dir ? Wih_b : Wih_f;
    const float* Whh = dir ? Whh_b : Whh_f;
    int n = lane & 15, kb = lane >> 4;
    int p, ksp;
    if (ks < 21)      { p = 0; ksp = ks; }
    else if (ks < 42) { p = 1; ksp = ks - 21; }
    else if (ks < 47) { p = 2; ksp = ks - 42; }
    else              { p = 3; ksp = ks - 47; }
    int j = cb * 16 + n;
    int row = (p == 0) ? j : (p == 1) ? 512 + j : 1024 + j;
    #pragma unroll
    for (int e = 0; e < 8; ++e) {
        int k = ksp * 32 + kb * 8 + e;
        float v;
        if (p == 3)      v = Whh[(size_t)row * 512 + k];
        else if (p == 2) v = (k < INPG_) ? Wih[(size_t)row * INPG_ + k] : 0.f;
        else v = (k < INPG_) ? Wih[(size_t)row * INPG_ + k]
               : (k < 160)   ? 0.f
               : Whh[(size_t)row * 512 + (k - 160)];
        WE[(size_t)id * 8 + e] = f2bf(v);
    }
}

__global__ void wfused_k(const float* __restrict__ Wih_d, const float* __restrict__ Wdec1,
                         float* __restrict__ Wf) {
    int id = blockIdx.x * 256 + threadIdx.x;
    if (id >= G3_ * H_) return;
    int r = id >> 9, c = id & 511;
    float s = 0.f;
    for (int m = 0; m < 128; ++m)
        s += Wih_d[(size_t)r * 128 + m] * Wdec1[(size_t)m * 512 + c];
    Wf[id] = s;
}

__global__ void bfi_k(const float* __restrict__ Wih_d, const float* __restrict__ b_dec1,
                      const float* __restrict__ bih_d, float* __restrict__ bfi) {
    int r = blockIdx.x * 256 + threadIdx.x;
    if (r >= G3_) return;
    float s = bih_d[r];
    for (int m = 0; m < 128; ++m)
        s += Wih_d[(size_t)r * 128 + m] * b_dec1[m];
    bfi[r] = s;
}

// decoder weight pack: WD chunks [cb*64 + p*16 + ks][64][8], K=512 each plane.
__global__ void pack_wd(const float* __restrict__ Wf, const float* __restrict__ Whh,
                        ushort* __restrict__ WD, int fused) {
    int id = blockIdx.x * 256 + threadIdx.x;
    int lane = id & 63;
    int rest = id >> 6;
    int ks = rest & 63;
    int cb = rest >> 6;
    if (cb >= 32) return;
    int p = ks >> 4, ksp = ks & 15;
    int n = lane & 15, kb = lane >> 4;
    int j = cb * 16 + n;
    int row = (p == 0) ? j : (p == 1) ? 512 + j : 1024 + j;
    #pragma unroll
    for (int e = 0; e < 8; ++e) {
        int k = ksp * 32 + kb * 8 + e;
        float v;
        if (p <= 1) v = fused ? (Wf[(size_t)row * 512 + k] + Whh[(size_t)row * 512 + k])
                              : Whh[(size_t)row * 512 + k];
        else if (p == 2) v = fused ? Wf[(size_t)row * 512 + k] : 0.f;
        else v = Whh[(size_t)row * 512 + k];
        WD[(size_t)id * 8 + e] = f2bf(v);
    }
}

__global__ void pack_wdec(const float* __restrict__ Wdec1, ushort* __restrict__ pk) {
    int id = blockIdx.x * 256 + threadIdx.x;
    if (id >= 8192) return;
    int lane = id & 63, ch = id >> 6;
    int nt = ch >> 4, ks = ch & 15;
    int n = nt * 16 + (lane & 15);
    int k0 = ks * 32 + (lane >> 4) * 8;
    #pragma unroll
    for (int e = 0; e < 8; ++e)
        pk[(size_t)id * 8 + e] = f2bf(Wdec1[(size_t)n * 512 + k0 + e]);
}

// poison-fill per-step exchange buffers with 0xFFFF (bf16 NaN)
__global__ void poison_k(ulonglong2* __restrict__ hb, ulonglong2* __restrict__ hist) {
    size_t id = (size_t)blockIdx.x * 256 + threadIdx.x;
    ulonglong2 p; p.x = ~0ull; p.y = ~0ull;
    if (id < (size_t)256 * 2 * 65536 / 8) hb[id] = p;
    if (id < (size_t)255 * 65536 / 8)     hist[id] = p;
}

__global__ void note0_k2(const float* __restrict__ x, float* __restrict__ out,
                         float* __restrict__ note0f) {
    int id = blockIdx.x * 256 + threadIdx.x;
    if (id >= B_ * IN_) return;
    int b = id >> 7, n = id & 127;
    float v = x[((size_t)b * T_) * INPG_ + n];
    out[((size_t)b * T_) * IN_ + n] = v;
    note0f[(size_t)b * 128 + n] = v;
}

__global__ void cvt_h0(const float* __restrict__ src, ushort* __restrict__ dst) {
    int id = blockIdx.x * 256 + threadIdx.x;
    if (id < B_ * H_) dst[id] = f2bf(src[id]);
}

__global__ void tile_w(const float* __restrict__ W, ushort4* __restrict__ out,
                       int N, int K, int KC) {
    int id = blockIdx.x * 256 + threadIdx.x;
    if (id >= KC * N) return;
    int kc = id / N, n = id - kc * N;
    int k = kc * 4;
    ushort4 u;
    u.x = f2bf(k + 0 < K ? W[(size_t)n * K + k + 0] : 0.f);
    u.y = f2bf(k + 1 < K ? W[(size_t)n * K + k + 1] : 0.f);
    u.z = f2bf(k + 2 < K ? W[(size_t)n * K + k + 2] : 0.f);
    u.w = f2bf(k + 3 < K ? W[(size_t)n * K + k + 3] : 0.f);
    out[(size_t)kc * N + n] = u;
}

#define MFMA16(a, b, c) __builtin_amdgcn_mfma_f32_16x16x32_bf16((a), (b), (c), 0, 0, 0)

// =============== persistent encoder ===============
// grid 256 = dir(2) x rt2(4) x cb(32); block = 128 thr (2 waves).
// Wave owns 16 rows x 16 cols x ALL 4 gate planes (dec_step1 structure).
// A-frags loaded directly global->regs; epilogue register-local; the loop
// has NO __syncthreads. Sync = data-as-flag retry on poisoned h buffers.
__global__ __launch_bounds__(128) void enc_persist(
    const ushort* __restrict__ xb16, const ushort* __restrict__ WE,
    ushort* __restrict__ hb,            // [256 t][2 dir][128][512] bf16
    float* __restrict__ hidden,         // [128][1024]
    const float* __restrict__ bih_f, const float* __restrict__ bhh_f,
    const float* __restrict__ bih_b, const float* __restrict__ bhh_b)
{
    __shared__ ushort Ws[63 * 512];      // 64.5 KB (shared by both waves)
    int bid = blockIdx.x;
    int dir = bid >> 7, rt2 = (bid >> 5) & 3, cb = bid & 31;
    int tid = threadIdx.x;
    int lane = tid & 63, wv = tid >> 6;
    int m = lane & 15, kb = lane >> 4;
    int rowbase = rt2 * 32 + wv * 16;    // wave's 16 batch rows
    const float* bih = dir ? bih_b : bih_f;
    const float* bhh = dir ? bhh_b : bhh_f;

    {
        const ushort* src = WE + (size_t)((dir * 32 + cb) * 63) * 512;
        for (int c = tid; c < 4032; c += 128)
            *(uint4*)&Ws[c * 8] = *(const uint4*)&src[c * 8];
    }
    __syncthreads();                     // Ws ready (only barrier in kernel)

    int j = cb * 16 + m;                 // output column
    int orow = rowbase + kb * 4;         // output row base (C-frag)
    float b_r = bih[j] + bhh[j];
    float b_z = bih[512 + j] + bhh[512 + j];
    float b_in = bih[1024 + j];
    float b_hn = bhh[1024 + j];
    float hc[4] = {0.f, 0.f, 0.f, 0.f};
    const ushort* Wl = &Ws[lane * 8];

    for (int t = 0; t < T_; ++t) {
        ushort* hout = hb + ((size_t)t * 2 + dir) * 65536;
        int tt = dir ? (255 - t) : t;
        const ushort* xr = xb16 + (size_t)tt * (B_ * 160)
                         + (size_t)(rowbase + m) * 160 + kb * 8;
        u64 hv[32];
        const ushort* hr = hb + (size_t)(t > 0 ? (t - 1) * 2 + dir : 0) * 65536
                         + (size_t)(rowbase + m) * 512 + kb * 8;
        if (t > 0) {
            #pragma unroll
            for (int ks = 0; ks < 16; ++ks) {     // 32 loads in flight
                hv[2 * ks]     = ld_h64(hr + ks * 32);
                hv[2 * ks + 1] = ld_h64(hr + ks * 32 + 4);
            }
        }
        f32x4 aR = {0.f,0.f,0.f,0.f}, aZ = {0.f,0.f,0.f,0.f};
        f32x4 aNx = {0.f,0.f,0.f,0.f}, aNh = {0.f,0.f,0.f,0.f};
        // x-part MFMAs overlap h load latency
        #pragma unroll
        for (int ks = 0; ks < 5; ++ks) {
            bf16x8 ax = *(const bf16x8*)(xr + ks * 32);
            aR  = MFMA16(ax, *(const bf16x8*)(Wl + (size_t)(0 + ks) * 512), aR);
            aZ  = MFMA16(ax, *(const bf16x8*)(Wl + (size_t)(21 + ks) * 512), aZ);
            aNx = MFMA16(ax, *(const bf16x8*)(Wl + (size_t)(42 + ks) * 512), aNx);
        }
        if (t > 0) {
            for (;;) {                            // batched validate+retry
                u64 bad = 0;
                #pragma unroll
                for (int i = 0; i < 32; ++i) bad |= badm(hv[i]);
                if (__all(bad == 0)) break;
                #pragma unroll
                for (int ks = 0; ks < 16; ++ks) {
                    hv[2 * ks]     = ld_h64(hr + ks * 32);
                    hv[2 * ks + 1] = ld_h64(hr + ks * 32 + 4);
                }
            }
            #pragma unroll
            for (int ks = 0; ks < 16; ++ks) {
                bf16x8 ah = mk_frag(hv[2 * ks], hv[2 * ks + 1]);
                aR  = MFMA16(ah, *(const bf16x8*)(Wl + (size_t)(5 + ks) * 512), aR);
                aZ  = MFMA16(ah, *(const bf16x8*)(Wl + (size_t)(26 + ks) * 512), aZ);
                aNh = MFMA16(ah, *(const bf16x8*)(Wl + (size_t)(47 + ks) * 512), aNh);
            }
        }
        #pragma unroll
        for (int i = 0; i < 4; ++i) {
            float r = sigf(aR[i] + b_r);
            float z = sigf(aZ[i] + b_z);
            float n = ftanh(aNx[i] + b_in + r * (aNh[i] + b_hn));
            hc[i] = (1.f - z) * n + z * hc[i];
            st_h16(hout + (size_t)(orow + i) * 512 + j, f2bf(hc[i]));
        }
        if (t == 255) {
            #pragma unroll
            for (int i = 0; i < 4; ++i)
                hidden[(size_t)(orow + i) * 1024 + dir * 512 + j] = hc[i];
        }
    }
}

// =============== decoder step 1 (one-shot, 1 wave/block) ===============
__global__ __launch_bounds__(64, 1) void dec_step1(
    const ushort* __restrict__ hdec0, const ushort* __restrict__ WD1,
    const float* __restrict__ h0f, const float* __restrict__ gi0,
    const float* __restrict__ bhh, ushort* __restrict__ hist0,
    float* __restrict__ h1f)
{
    int bid = blockIdx.x;
    int rt = bid >> 5, cb = bid & 31;
    int lane = threadIdx.x;
    int m = lane & 15, kb = lane >> 4;
    int arow = rt * 16 + m;
    int j = cb * 16 + m;
    int orow = rt * 16 + kb * 4;
    const ushort* hr = hdec0 + (size_t)arow * 512 + kb * 8;
    bf16x8 af[16];
    #pragma unroll
    for (int ks = 0; ks < 16; ++ks)
        af[ks] = *(const bf16x8*)(hr + ks * 32);
    const ushort* w1 = WD1 + (size_t)(cb * 64) * 512 + lane * 8;
    f32x4 aR = {0.f,0.f,0.f,0.f}, aZ = {0.f,0.f,0.f,0.f}, aGh = {0.f,0.f,0.f,0.f};
    #pragma unroll
    for (int ks = 0; ks < 16; ++ks) {
        aR = MFMA16(af[ks], *(const bf16x8*)(w1 + (size_t)ks * 512), aR);
        aZ = MFMA16(af[ks], *(const bf16x8*)(w1 + (size_t)(16 + ks) * 512), aZ);
        aGh = MFMA16(af[ks], *(const bf16x8*)(w1 + (size_t)(48 + ks) * 512), aGh);
    }
    float bh_r = bhh[j], bh_z = bhh[512 + j], bh_n = bhh[1024 + j];
    #pragma unroll
    for (int i = 0; i < 4; ++i) {
        int rg = orow + i;
        float gr = gi0[(size_t)rg * G3_ + j];
        float gz = gi0[(size_t)rg * G3_ + 512 + j];
        float gn = gi0[(size_t)rg * G3_ + 1024 + j];
        float h0 = h0f[(size_t)rg * 512 + j];
        float r = sigf(aR[i] + gr + bh_r);
        float z = sigf(aZ[i] + gz + bh_z);
        float n = ftanh(gn + r * (aGh[i] + bh_n));
        float h1 = (1.f - z) * n + z * h0;
        h1f[(size_t)rg * 512 + j] = h1;
        hist0[(size_t)rg * 512 + j] = f2bf(h1);
    }
}

// =============== persistent decoder (t = 2..255) ===============
// grid 128 = rt2(4) x cb(32); block 128 thr (2 waves). Same barrier-free
// wave-owns-everything structure as enc; weights (4 planes) in shared LDS.
__global__ __launch_bounds__(128) void dec_persist(
    const ushort* __restrict__ WD2, ushort* __restrict__ hist,  // [255][128][512]
    const float* __restrict__ h1f, const float* __restrict__ bfi,
    const float* __restrict__ bhh)
{
    __shared__ ushort Ws[64 * 512];      // 64 KB
    int bid = blockIdx.x;
    int rt2 = bid >> 5, cb = bid & 31;
    int tid = threadIdx.x;
    int lane = tid & 63, wv = tid >> 6;
    int m = lane & 15, kb = lane >> 4;
    int rowbase = rt2 * 32 + wv * 16;
    {
        const ushort* src = WD2 + (size_t)(cb * 64) * 512;
        for (int c = tid; c < 4096; c += 128)
            *(uint4*)&Ws[c * 8] = *(const uint4*)&src[c * 8];
    }
    __syncthreads();
    int j = cb * 16 + m;
    int orow = rowbase + kb * 4;
    float f_r = bfi[j] + bhh[j];
    float f_z = bfi[512 + j] + bhh[512 + j];
    float f_in = bfi[1024 + j];
    float f_hn = bhh[1024 + j];
    float hc[4];
    #pragma unroll
    for (int i = 0; i < 4; ++i)
        hc[i] = h1f[(size_t)(orow + i) * 512 + j];
    const ushort* Wl = &Ws[lane * 8];

    for (int t = 2; t < T_; ++t) {
        const ushort* hr = hist + (size_t)(t - 2) * 65536
                         + (size_t)(rowbase + m) * 512 + kb * 8;
        u64 hv[32];
        for (;;) {
            #pragma unroll
            for (int ks = 0; ks < 16; ++ks) {
                hv[2 * ks]     = ld_h64(hr + ks * 32);
                hv[2 * ks + 1] = ld_h64(hr + ks * 32 + 4);
            }
            u64 bad = 0;
            #pragma unroll
            for (int i = 0; i < 32; ++i) bad |= badm(hv[i]);
            if (__all(bad == 0)) break;
        }
        f32x4 aR = {0.f,0.f,0.f,0.f}, aZ = {0.f,0.f,0.f,0.f};
        f32x4 aGi = {0.f,0.f,0.f,0.f}, aGh = {0.f,0.f,0.f,0.f};
        #pragma unroll
        for (int ks = 0; ks < 16; ++ks) {
            bf16x8 a = mk_frag(hv[2 * ks], hv[2 * ks + 1]);
            aR  = MFMA16(a, *(const bf16x8*)(Wl + (size_t)ks * 512), aR);
            aZ  = MFMA16(a, *(const bf16x8*)(Wl + (size_t)(16 + ks) * 512), aZ);
            aGi = MFMA16(a, *(const bf16x8*)(Wl + (size_t)(32 + ks) * 512), aGi);
            aGh = MFMA16(a, *(const bf16x8*)(Wl + (size_t)(48 + ks) * 512), aGh);
        }
        ushort* hdst = hist + (size_t)(t - 1) * 65536;
        #pragma unroll
        for (int i = 0; i < 4; ++i) {
            float r = sigf(aR[i] + f_r);
            float z = sigf(aZ[i] + f_z);
            float n = ftanh(aGi[i] + f_in + r * (aGh[i] + f_hn));
            hc[i] = (1.f - z) * n + z * hc[i];
            st_h16(hdst + (size_t)(orow + i) * 512 + j, f2bf(hc[i]));
        }
    }
}

// =============== notes GEMM (MFMA): hist @ Wdec1.T + b -> out[:,1:,:] ===============
__global__ __launch_bounds__(256) void notes_mfma(
    const ushort* __restrict__ hist, const ushort* __restrict__ pk,
    const float* __restrict__ bd, float* __restrict__ out)
{
    __shared__ ushort hs[32 * DRS];
    int m0 = blockIdx.x * 32;
    int tid = threadIdx.x;
    #pragma unroll
    for (int i = 0; i < 8; ++i) {
        int c = tid + i * 256;
        int row = c >> 6, off = c & 63;
        ulonglong2 v = *(const ulonglong2*)(hist + (size_t)(m0 + row) * 512 + off * 8);
        char* d = (char*)hs + row * (DRS * 2) + off * 16;
        *(u64*)d = v.x; *(u64*)(d + 8) = v.y;
    }
    __syncthreads();
    int lane = tid & 63, wv = tid >> 6;
    int m = lane & 15, kb = lane >> 4;
    int nt0 = wv * 2;
    f32x4 acc00 = {0.f,0.f,0.f,0.f}, acc01 = {0.f,0.f,0.f,0.f};
    f32x4 acc10 = {0.f,0.f,0.f,0.f}, acc11 = {0.f,0.f,0.f,0.f};
    for (int ks = 0; ks < 16; ++ks) {
        bf16x8 a0 = lds_frag(&hs[m * DRS + ks * 32 + kb * 8]);
        bf16x8 a1 = lds_frag(&hs[(16 + m) * DRS + ks * 32 + kb * 8]);
        bf16x8 bf0 = *(const bf16x8*)&pk[(size_t)((nt0 * 16 + ks) * 64 + lane) * 8];
        bf16x8 bf1 = *(const bf16x8*)&pk[(size_t)(((nt0 + 1) * 16 + ks) * 64 + lane) * 8];
        acc00 = MFMA16(a0, bf0, acc00);
        acc01 = MFMA16(a0, bf1, acc01);
        acc10 = MFMA16(a1, bf0, acc10);
        acc11 = MFMA16(a1, bf1, acc11);
    }
    int n0 = nt0 * 16 + (lane & 15), n1 = (nt0 + 1) * 16 + (lane & 15);
    #pragma unroll
    for (int i = 0; i < 4; ++i) {
        int r0 = m0 + kb * 4 + i;
        int r1 = r0 + 16;
        int t0 = r0 >> 7, b0r = r0 & 127;
        int t1 = r1 >> 7, b1r = r1 & 127;
        out[((size_t)b0r * T_ + (t0 + 1)) * IN_ + n0] = acc00[i] + bd[n0];
        out[((size_t)b0r * T_ + (t0 + 1)) * IN_ + n1] = acc01[i] + bd[n1];
        out[((size_t)b1r * T_ + (t1 + 1)) * IN_ + n0] = acc10[i] + bd[n0];
        out[((size_t)b1r * T_ + (t1 + 1)) * IN_ + n1] = acc11[i] + bd[n1];
    }
}

// =============== MLP GEMM (fp32 A, bf16 tiled W) ===============
__global__ __launch_bounds__(256) void gemm_t4(
    const float* __restrict__ A, const ushort4* __restrict__ Wt,
    const float* __restrict__ bias, float* __restrict__ C,
    int M, int N, int K, int act)
{
    int nb = blockIdx.x, mb = blockIdx.y;
    int tid = threadIdx.x;
    int n = nb * 64 + (tid & 63);
    int mq = tid >> 6;
    int m0 = mb * 32;
    __shared__ float Asm[32][36];
    float acc[8];
    #pragma unroll
    for (int i = 0; i < 8; ++i) acc[i] = 0.f;
    for (int k0 = 0; k0 < K; k0 += 32) {
        int r = tid >> 3, c = (tid & 7) << 2;
        float4 v = *(const float4*)&A[(size_t)(m0 + r) * K + k0 + c];
        Asm[r][c] = v.x; Asm[r][c+1] = v.y; Asm[r][c+2] = v.z; Asm[r][c+3] = v.w;
        __syncthreads();
        #pragma unroll
        for (int kc = 0; kc < 8; ++kc) {
            float w0 = 0.f, w1 = 0.f, w2 = 0.f, w3 = 0.f;
            if (n < N) {
                ushort4 u = Wt[(size_t)((k0 >> 2) + kc) * N + n];
                w0 = bf2f(u.x); w1 = bf2f(u.y); w2 = bf2f(u.z); w3 = bf2f(u.w);
            }
            #pragma unroll
            for (int i = 0; i < 8; ++i) {
                int mm = mq * 8 + i;
                acc[i] += Asm[mm][kc*4+0]*w0 + Asm[mm][kc*4+1]*w1
                        + Asm[mm][kc*4+2]*w2 + Asm[mm][kc*4+3]*w3;
            }
        }
        __syncthreads();
    }
    if (n < N) {
        #pragma unroll
        for (int i = 0; i < 8; ++i) {
            int mm = m0 + mq * 8 + i;
            float v = acc[i] + bias[n];
            if (act == 1) v = (v >= 0.f) ? v : 0.01f * v;
            C[(size_t)mm * N + n] = v;
        }
    }
}

__global__ void z_k(const float* __restrict__ out, const float* __restrict__ eps,
                    const float* __restrict__ genre, float* __restrict__ zc) {
    int id = blockIdx.x * 256 + threadIdx.x;
    if (id >= B_ * L_) return;
    int b = id >> 8, c = id & 255;
    float v;
    if (c < LG_) {
        float mu = out[MU_OFF + (size_t)b * LG_ + c];
        float lv = out[LV_OFF + (size_t)b * LG_ + c];
        v = mu + expf(0.5f * lv) * eps[(size_t)b * LG_ + c];
    } else {
        v = genre[(size_t)b * G_ + (c - LG_)];
    }
    zc[id] = v;
}

// =============== host ===============
extern "C" void kernel_launch(void* const* d_in, const int* in_sizes, int n_in,
                              void* d_out, int out_size, void* d_ws, size_t ws_size,
                              hipStream_t stream) {
    (void)in_sizes; (void)n_in; (void)out_size; (void)ws_size;
    const float* x      = (const float*)d_in[0];
    const float* genre  = (const float*)d_in[1];
    const float* eps    = (const float*)d_in[2];
    const float* Wih_e  = (const float*)d_in[3];
    const float* Whh_e  = (const float*)d_in[4];
    const float* bih_e  = (const float*)d_in[5];
    const float* bhh_e  = (const float*)d_in[6];
    const float* Wih_be = (const float*)d_in[7];
    const float* Whh_be = (const float*)d_in[8];
    const float* bih_be = (const float*)d_in[9];
    const float* bhh_be = (const float*)d_in[10];
    const float* Wih_d  = (const float*)d_in[11];
    const float* Whh_d  = (const float*)d_in[12];
    const float* bih_d  = (const float*)d_in[13];
    const float* bhh_d  = (const float*)d_in[14];
    const float* W_mu0  = (const float*)d_in[15];
    const float* b_mu0  = (const float*)d_in[16];
    const float* W_mu1  = (const float*)d_in[17];
    const float* b_mu1  = (const float*)d_in[18];
    const float* W_lv0  = (const float*)d_in[19];
    const float* b_lv0  = (const float*)d_in[20];
    const float* W_lv1  = (const float*)d_in[21];
    const float* b_lv1  = (const float*)d_in[22];
    const float* W_lat0 = (const float*)d_in[23];
    const float* b_lat0 = (const float*)d_in[24];
    const float* W_lat1 = (const float*)d_in[25];
    const float* b_lat1 = (const float*)d_in[26];
    const float* W_dec1 = (const float*)d_in[27];
    const float* b_dec1 = (const float*)d_in[28];
    float* out = (float*)d_out;

    char* ws = (char*)d_ws;
    size_t off = 0;
    auto alloc = [&](size_t bytes) -> char* {
        char* p = ws + off;
        off = (off + bytes + 255) & ~(size_t)255;
        return p;
    };
    ushort* xb16  = (ushort*)alloc((size_t)T_ * B_ * 160 * 2);
    ushort* WE    = (ushort*)alloc((size_t)2 * 32 * 63 * 512 * 2);
    ushort* WD2   = (ushort*)alloc((size_t)32 * 64 * 512 * 2);
    ushort* WD1   = (ushort*)alloc((size_t)32 * 64 * 512 * 2);
    float*  Wf    = (float*)alloc((size_t)G3_ * H_ * 4);
    float*  bfi   = (float*)alloc(G3_ * 4);
    ushort* hb_e  = (ushort*)alloc((size_t)256 * 2 * 65536 * 2);   // 67 MB
    ushort* hist  = (ushort*)alloc((size_t)255 * 65536 * 2);       // 33 MB
    ushort* hdec0 = (ushort*)alloc((size_t)65536 * 2);
    ushort* pkdec = (ushort*)alloc((size_t)8192 * 8 * 2);
    float*  note0f= (float*)alloc((size_t)B_ * 128 * 4);
    float*  gi0   = (float*)alloc((size_t)B_ * G3_ * 4);
    float*  hidden= (float*)alloc((size_t)B_ * E_ * 4);
    float*  t0buf = (float*)alloc((size_t)B_ * E_ * 4);
    float*  t1buf = (float*)alloc((size_t)B_ * E_ * 4);
    float*  zcbuf = (float*)alloc((size_t)B_ * L_ * 4);
    float*  t2buf = (float*)alloc((size_t)B_ * L_ * 4);
    float*  t3buf = (float*)alloc((size_t)B_ * H_ * 4);
    float*  h1f   = (float*)alloc((size_t)B_ * H_ * 4);

    ushort4* T_Wmu0  = (ushort4*)alloc((size_t)256 * E_ * 8);
    ushort4* T_Wmu1  = (ushort4*)alloc((size_t)256 * LG_ * 8);
    ushort4* T_Wlv0  = (ushort4*)alloc((size_t)256 * E_ * 8);
    ushort4* T_Wlv1  = (ushort4*)alloc((size_t)256 * LG_ * 8);
    ushort4* T_Wlat0 = (ushort4*)alloc((size_t)64 * L_ * 8);
    ushort4* T_Wlat1 = (ushort4*)alloc((size_t)64 * H_ * 8);
    ushort4* T_Wihd  = (ushort4*)alloc((size_t)32 * G3_ * 8);

    // ---- prep ----
    xpad_k<<<(T_ * B_ * 160 + 255) / 256, 256, 0, stream>>>(x, xb16);
    pack_we<<<1008, 256, 0, stream>>>(Wih_e, Whh_e, Wih_be, Whh_be, WE);
    wfused_k<<<(G3_ * H_ + 255) / 256, 256, 0, stream>>>(Wih_d, W_dec1, Wf);
    bfi_k<<<6, 256, 0, stream>>>(Wih_d, b_dec1, bih_d, bfi);
    pack_wd<<<512, 256, 0, stream>>>(Wf, Whh_d, WD2, 1);
    pack_wd<<<512, 256, 0, stream>>>(Wf, Whh_d, WD1, 0);
    pack_wdec<<<32, 256, 0, stream>>>(W_dec1, pkdec);
    poison_k<<<16384, 256, 0, stream>>>((ulonglong2*)hb_e, (ulonglong2*)hist);
    note0_k2<<<(B_ * IN_ + 255) / 256, 256, 0, stream>>>(x, out, note0f);

    auto tile = [&](const float* W, ushort4* dst, int N, int K) {
        int KC = (K + 3) / 4;
        tile_w<<<(KC * N + 255) / 256, 256, 0, stream>>>(W, dst, N, K, KC);
    };
    tile(W_mu0,  T_Wmu0,  E_,  E_);
    tile(W_mu1,  T_Wmu1,  LG_, E_);
    tile(W_lv0,  T_Wlv0,  E_,  E_);
    tile(W_lv1,  T_Wlv1,  LG_, E_);
    tile(W_lat0, T_Wlat0, L_,  L_);
    tile(W_lat1, T_Wlat1, H_,  L_);
    tile(Wih_d,  T_Wihd,  G3_, IN_);

    // ---- persistent bidirectional encoder (barrier-free wave-local) ----
    enc_persist<<<256, 128, 0, stream>>>(xb16, WE, hb_e, hidden,
                                         bih_e, bhh_e, bih_be, bhh_be);

    // ---- MLP bottleneck ----
    {
        dim3 g1(16, 4), g2(4, 4), g3(4, 4), g4(8, 4), g5(24, 4);
        gemm_t4<<<g1, 256, 0, stream>>>(hidden, T_Wmu0, b_mu0, t0buf, B_, E_, E_, 1);
        gemm_t4<<<g2, 256, 0, stream>>>(t0buf, T_Wmu1, b_mu1, out + MU_OFF, B_, LG_, E_, 0);
        gemm_t4<<<g1, 256, 0, stream>>>(hidden, T_Wlv0, b_lv0, t1buf, B_, E_, E_, 1);
        gemm_t4<<<g2, 256, 0, stream>>>(t1buf, T_Wlv1, b_lv1, out + LV_OFF, B_, LG_, E_, 0);
        z_k<<<(B_ * L_ + 255) / 256, 256, 0, stream>>>(out, eps, genre, zcbuf);
        gemm_t4<<<g3, 256, 0, stream>>>(zcbuf, T_Wlat0, b_lat0, t2buf, B_, L_, L_, 1);
        gemm_t4<<<g4, 256, 0, stream>>>(t2buf, T_Wlat1, b_lat1, t3buf, B_, H_, L_, 0);
        gemm_t4<<<g5, 256, 0, stream>>>(note0f, T_Wihd, bih_d, gi0, B_, G3_, IN_, 0);
    }
    cvt_h0<<<(B_ * H_ + 255) / 256, 256, 0, stream>>>(t3buf, hdec0);

    // ---- decoder step 1 + persistent decoder (t=2..255) ----
    dec_step1<<<256, 64, 0, stream>>>(hdec0, WD1, t3buf, gi0, bhh_d, hist, h1f);
    dec_persist<<<128, 128, 0, stream>>>(WD2, hist, h1f, bfi, bhh_d);

    // ---- all notes (MFMA GEMM) ----
    notes_mfma<<<1020, 256, 0, stream>>>(hist, pkdec, b_dec1, out);
}

// Round 14
// 2197.211 us; speedup vs baseline: 1.7637x; 1.7637x over previous
//
#include <hip/hip_runtime.h>

#define B_ 128
#define T_ 256
#define IN_ 128
#define G_ 5
#define H_ 512
#define G3_ 1536
#define E_ 1024
#define L_ 256
#define LG_ 251
#define INPG_ 133

#define MU_OFF (B_*T_*IN_)            /* 4194304 */
#define LV_OFF (MU_OFF + B_*LG_)      /* 4226432 */

// LDS row strides: stride_dwords mod 32 = 6 (gcd 2 with 32) -> 16 distinct
// bank starts across the 16 m-rows -> near-conflict-free b64 reads.
#define ERS 684   /* enc As row stride (ushorts); 1368 B */
#define DRS 524   /* dec As row stride; 1048 B */

typedef __attribute__((ext_vector_type(8))) short bf16x8;
typedef __attribute__((ext_vector_type(4))) float f32x4;
typedef unsigned long long u64;

__device__ __forceinline__ float bf2f(unsigned short s) {
    return __uint_as_float(((unsigned)s) << 16);
}
__device__ __forceinline__ unsigned short f2bf(float f) {
    unsigned x = __float_as_uint(f);
    unsigned r = (x + 0x7fffu + ((x >> 16) & 1u)) >> 16;
    return (unsigned short)r;
}
__device__ __forceinline__ float sigf(float v) {
    return __builtin_amdgcn_rcpf(1.f + __expf(-v));
}
__device__ __forceinline__ float ftanh(float x) {
    x = fminf(15.f, fmaxf(-15.f, x));
    float e = __expf(2.f * x);
    return (e - 1.f) * __builtin_amdgcn_rcpf(e + 1.f);
}
// ---- agent-scope (cross-XCD coherent) ops ----
__device__ __forceinline__ u64 ld_h64(const void* p) {
    return __hip_atomic_load((const u64*)p, __ATOMIC_RELAXED, __HIP_MEMORY_SCOPE_AGENT);
}
__device__ __forceinline__ void st_h32(void* p, unsigned v) {
    __hip_atomic_store((unsigned*)p, v, __ATOMIC_RELAXED, __HIP_MEMORY_SCOPE_AGENT);
}
// nonzero iff some 16-bit lane of v equals 0xFFFF (bf16 NaN poison)
__device__ __forceinline__ u64 badm(u64 v) {
    u64 x = ~v;
    return (x - 0x0001000100010001ull) & ~x & 0x8000800080008000ull;
}
__device__ __forceinline__ bf16x8 mk_frag(u64 lo, u64 hi) {
    bf16x8 a;
    ((u64*)&a)[0] = lo; ((u64*)&a)[1] = hi;
    return a;
}
// LDS fragment read: two 8B-aligned b64 reads (conflict-free at stride 6 mod 32)
__device__ __forceinline__ bf16x8 lds_frag(const ushort* p) {
    u64 lo = *(const u64*)p;
    u64 hi = *(const u64*)(p + 4);
    return mk_frag(lo, hi);
}

// =============== prep kernels ===============

__global__ void xpad_k(const float* __restrict__ x, ushort* __restrict__ xb) {
    int id = blockIdx.x * 256 + threadIdx.x;
    if (id >= T_ * B_ * 160) return;
    int t = id / (B_ * 160);
    int rem = id - t * (B_ * 160);
    int b = rem / 160, c = rem - b * 160;
    float v = (c < INPG_) ? x[((size_t)b * T_ + t) * INPG_ + c] : 0.f;
    xb[id] = f2bf(v);
}

// encoder weight pack: WE chunks [(dir*32+cb)*63 + ks][64 lanes][8 bf16]
// planes: ks 0..20 r(cat672), 21..41 z(cat672), 42..46 nx(K160), 47..62 nh(K512)
__global__ void pack_we(const float* __restrict__ Wih_f, const float* __restrict__ Whh_f,
                        const float* __restrict__ Wih_b, const float* __restrict__ Whh_b,
                        ushort* __restrict__ WE) {
    int id = blockIdx.x * 256 + threadIdx.x;
    int lane = id & 63;
    int rest = id >> 6;
    int ks = rest % 63;
    int cb = (rest / 63) & 31;
    int dir = rest / (63 * 32);
    if (dir >= 2) return;
    const float* Wih = dir ? Wih_b : Wih_f;
    const float* Whh = dir ? Whh_b : Whh_f;
    int n = lane & 15, kb = lane >> 4;
    int p, ksp;
    if (ks < 21)      { p = 0; ksp = ks; }
    else if (ks < 42) { p = 1; ksp = ks - 21; }
    else if (ks < 47) { p = 2; ksp = ks - 42; }
    else              { p = 3; ksp = ks - 47; }
    int j = cb * 16 + n;
    int row = (p == 0) ? j : (p == 1) ? 512 + j : 1024 + j;
    #pragma unroll
    for (int e = 0; e < 8; ++e) {
        int k = ksp * 32 + kb * 8 + e;
        float v;
        if (p == 3)      v = Whh[(size_t)row * 512 + k];
        else if (p == 2) v = (k < INPG_) ? Wih[(size_t)row * INPG_ + k] : 0.f;
        else v = (k < INPG_) ? Wih[(size_t)row * INPG_ + k]
               : (k < 160)   ? 0.f
               : Whh[(size_t)row * 512 + (k - 160)];
        WE[(size_t)id * 8 + e] = f2bf(v);
    }
}

__global__ void wfused_k(const float* __restrict__ Wih_d, const float* __restrict__ Wdec1,
                         float* __restrict__ Wf) {
    int id = blockIdx.x * 256 + threadIdx.x;
    if (id >= G3_ * H_) return;
    int r = id >> 9, c = id & 511;
    float s = 0.f;
    for (int m = 0; m < 128; ++m)
        s += Wih_d[(size_t)r * 128 + m] * Wdec1[(size_t)m * 512 + c];
    Wf[id] = s;
}

__global__ void bfi_k(const float* __restrict__ Wih_d, const float* __restrict__ b_dec1,
                      const float* __restrict__ bih_d, float* __restrict__ bfi) {
    int r = blockIdx.x * 256 + threadIdx.x;
    if (r >= G3_) return;
    float s = bih_d[r];
    for (int m = 0; m < 128; ++m)
        s += Wih_d[(size_t)r * 128 + m] * b_dec1[m];
    bfi[r] = s;
}

// decoder weight pack: WD chunks [cb*64 + p*16 + ks][64][8], K=512 each plane.
__global__ void pack_wd(const float* __restrict__ Wf, const float* __restrict__ Whh,
                        ushort* __restrict__ WD, int fused) {
    int id = blockIdx.x * 256 + threadIdx.x;
    int lane = id & 63;
    int rest = id >> 6;
    int ks = rest & 63;
    int cb = rest >> 6;
    if (cb >= 32) return;
    int p = ks >> 4, ksp = ks & 15;
    int n = lane & 15, kb = lane >> 4;
    int j = cb * 16 + n;
    int row = (p == 0) ? j : (p == 1) ? 512 + j : 1024 + j;
    #pragma unroll
    for (int e = 0; e < 8; ++e) {
        int k = ksp * 32 + kb * 8 + e;
        float v;
        if (p <= 1) v = fused ? (Wf[(size_t)row * 512 + k] + Whh[(size_t)row * 512 + k])
                              : Whh[(size_t)row * 512 + k];
        else if (p == 2) v = fused ? Wf[(size_t)row * 512 + k] : 0.f;
        else v = Whh[(size_t)row * 512 + k];
        WD[(size_t)id * 8 + e] = f2bf(v);
    }
}

__global__ void pack_wdec(const float* __restrict__ Wdec1, ushort* __restrict__ pk) {
    int id = blockIdx.x * 256 + threadIdx.x;
    if (id >= 8192) return;
    int lane = id & 63, ch = id >> 6;
    int nt = ch >> 4, ks = ch & 15;
    int n = nt * 16 + (lane & 15);
    int k0 = ks * 32 + (lane >> 4) * 8;
    #pragma unroll
    for (int e = 0; e < 8; ++e)
        pk[(size_t)id * 8 + e] = f2bf(Wdec1[(size_t)n * 512 + k0 + e]);
}

// poison-fill per-step exchange buffers with 0xFFFF (bf16 NaN)
__global__ void poison_k(ulonglong2* __restrict__ hb, ulonglong2* __restrict__ hist) {
    size_t id = (size_t)blockIdx.x * 256 + threadIdx.x;
    ulonglong2 p; p.x = ~0ull; p.y = ~0ull;
    if (id < (size_t)256 * 2 * 65536 / 8) hb[id] = p;
    if (id < (size_t)255 * 65536 / 8)     hist[id] = p;
}

__global__ void note0_k2(const float* __restrict__ x, float* __restrict__ out,
                         float* __restrict__ note0f) {
    int id = blockIdx.x * 256 + threadIdx.x;
    if (id >= B_ * IN_) return;
    int b = id >> 7, n = id & 127;
    float v = x[((size_t)b * T_) * INPG_ + n];
    out[((size_t)b * T_) * IN_ + n] = v;
    note0f[(size_t)b * 128 + n] = v;
}

__global__ void cvt_h0(const float* __restrict__ src, ushort* __restrict__ dst) {
    int id = blockIdx.x * 256 + threadIdx.x;
    if (id < B_ * H_) dst[id] = f2bf(src[id]);
}

__global__ void tile_w(const float* __restrict__ W, ushort4* __restrict__ out,
                       int N, int K, int KC) {
    int id = blockIdx.x * 256 + threadIdx.x;
    if (id >= KC * N) return;
    int kc = id / N, n = id - kc * N;
    int k = kc * 4;
    ushort4 u;
    u.x = f2bf(k + 0 < K ? W[(size_t)n * K + k + 0] : 0.f);
    u.y = f2bf(k + 1 < K ? W[(size_t)n * K + k + 1] : 0.f);
    u.z = f2bf(k + 2 < K ? W[(size_t)n * K + k + 2] : 0.f);
    u.w = f2bf(k + 3 < K ? W[(size_t)n * K + k + 3] : 0.f);
    out[(size_t)kc * N + n] = u;
}

#define MFMA16(a, b, c) __builtin_amdgcn_mfma_f32_16x16x32_bf16((a), (b), (c), 0, 0, 0)

// =============== persistent encoder ===============
// grid 256 = dir(2) x bt(4) x cb(32); block 256 = 4 waves (gate planes).
// LDS weights; data-as-flag batched retry; h-loads issued first, x-part
// MFMAs (operands in LDS) run while loads are in flight; validation after.
__global__ __launch_bounds__(256) void enc_persist(
    const ushort* __restrict__ xb16, const ushort* __restrict__ WE,
    ushort* __restrict__ hb,            // [256 t][2 dir][128][512] bf16
    float* __restrict__ hidden,         // [128][1024]
    const float* __restrict__ bih_f, const float* __restrict__ bhh_f,
    const float* __restrict__ bih_b, const float* __restrict__ bhh_b)
{
    __shared__ ushort As[32 * ERS];      // x bytes 0..319 | h bytes 320..1343
    __shared__ ushort Ws[63 * 512];      // 64.5 KB
    __shared__ float gs[4][512];         // 8 KB
    int bid = blockIdx.x;
    int dir = bid >> 7, bt = (bid >> 5) & 3, cb = bid & 31;
    int b0 = bt * 32;
    int tid = threadIdx.x;
    const float* bih = dir ? bih_b : bih_f;
    const float* bhh = dir ? bhh_b : bhh_f;

    // weight slice -> LDS (once)
    {
        const ushort* src = WE + (size_t)((dir * 32 + cb) * 63) * 512;
        for (int c = tid; c < 4032; c += 256)
            *(uint4*)&Ws[c * 8] = *(const uint4*)&src[c * 8];
    }
    // zero h region of As (t=0 reads zeros)
    for (int i = 0; i < 16; ++i) {
        int c = tid + i * 256;
        int row = c >> 7, off = c & 127;
        *(u64*)((char*)As + row * (ERS * 2) + 320 + off * 8) = 0ull;
    }
    // stage x for t=0
    {
        const ushort* xr = xb16 + (size_t)(dir ? 255 : 0) * (B_ * 160);
        for (int i = 0; i < 3; ++i) {
            int c = tid + i * 256;
            if (c < 640) {
                int row = c / 20, off = c - row * 20;
                ulonglong2 v = *(const ulonglong2*)(xr + (size_t)(b0 + row) * 160 + off * 8);
                char* d = (char*)As + row * (ERS * 2) + off * 16;
                *(u64*)d = v.x; *(u64*)(d + 8) = v.y;
            }
        }
    }
    int bA = tid >> 3;
    int j0 = cb * 16 + 2 * (tid & 7), j1 = j0 + 1;
    float b_r0 = bih[j0] + bhh[j0],             b_r1 = bih[j1] + bhh[j1];
    float b_z0 = bih[512 + j0] + bhh[512 + j0], b_z1 = bih[512 + j1] + bhh[512 + j1];
    float b_in0 = bih[1024 + j0],               b_in1 = bih[1024 + j1];
    float b_hn0 = bhh[1024 + j0],               b_hn1 = bhh[1024 + j1];
    float hc0 = 0.f, hc1 = 0.f;

    int lane = tid & 63, wv = tid >> 6;
    int m = lane & 15, kb = lane >> 4;
    // x-part (waves 0,1,2): B plane offsets 0/21/42; h-part (waves 0,1,3): 5/26/47
    int xB = (wv == 0) ? 0 : (wv == 1) ? 21 : 42;       // wv3 unused
    int hB = (wv == 0) ? 5 : (wv == 1) ? 26 : 47;       // wv2 unused
    int axi0 = m * ERS + kb * 8;
    int axi1 = (16 + m) * ERS + kb * 8;
    int ahi0 = m * ERS + 160 + kb * 8;
    int ahi1 = (16 + m) * ERS + 160 + kb * 8;

    __syncthreads();                     // initial staging visible

    for (int t = 0; t < T_; ++t) {
        ushort* hout = hb + ((size_t)t * 2 + dir) * 65536;
        const ushort* hin = hb + ((size_t)(t - 1) * 2 + dir) * 65536;
        u64 vb[16];
        if (t > 0) {
            // issue all 16 h loads (in flight during x-part MFMAs)
            #pragma unroll
            for (int i = 0; i < 16; ++i) {
                int c = tid + i * 256;
                int row = c >> 7, off = c & 127;
                vb[i] = ld_h64(hin + (size_t)(b0 + row) * 512 + off * 4);
            }
        }
        f32x4 acc0 = {0.f,0.f,0.f,0.f}, acc1 = {0.f,0.f,0.f,0.f};
        // x-part MFMAs overlap the load latency (waves 0,1,2; operands in LDS)
        if (wv != 3) {
            const ushort* Bx = &Ws[xB * 512 + lane * 8];
            #pragma unroll
            for (int ks = 0; ks < 5; ++ks) {
                bf16x8 bfr = *(const bf16x8*)(Bx + (size_t)ks * 512);
                acc0 = MFMA16(lds_frag(&As[axi0 + ks * 32]), bfr, acc0);
                acc1 = MFMA16(lds_frag(&As[axi1 + ks * 32]), bfr, acc1);
            }
        }
        if (t > 0) {
            // validate; on any poison, re-issue the whole batch (R9-proven)
            for (;;) {
                u64 bad = 0;
                #pragma unroll
                for (int i = 0; i < 16; ++i) bad |= badm(vb[i]);
                if (__all(bad == 0)) break;
                #pragma unroll
                for (int i = 0; i < 16; ++i) {
                    int c = tid + i * 256;
                    int row = c >> 7, off = c & 127;
                    vb[i] = ld_h64(hin + (size_t)(b0 + row) * 512 + off * 4);
                }
            }
            #pragma unroll
            for (int i = 0; i < 16; ++i) {
                int c = tid + i * 256;
                int row = c >> 7, off = c & 127;
                *(u64*)((char*)As + row * (ERS * 2) + 320 + off * 8) = vb[i];
            }
        }
        __syncthreads();                 // A: h region ready
        // h-part MFMAs (waves 0,1,3); wave 2 idle
        if (wv != 2) {
            const ushort* Bh = &Ws[hB * 512 + lane * 8];
            for (int ks = 0; ks < 16; ++ks) {
                bf16x8 bfr = *(const bf16x8*)(Bh + (size_t)ks * 512);
                acc0 = MFMA16(lds_frag(&As[ahi0 + ks * 32]), bfr, acc0);
                acc1 = MFMA16(lds_frag(&As[ahi1 + ks * 32]), bfr, acc1);
            }
        }
        #pragma unroll
        for (int i = 0; i < 4; ++i) {
            gs[wv][(kb * 4 + i) * 16 + m] = acc0[i];
            gs[wv][(16 + kb * 4 + i) * 16 + m] = acc1[i];
        }
        __syncthreads();                 // B: gs ready; all As reads done
        {
            int o0 = 2 * tid, o1 = o0 + 1;
            float r0 = sigf(gs[0][o0] + b_r0);
            float z0 = sigf(gs[1][o0] + b_z0);
            float n0 = ftanh(gs[2][o0] + b_in0 + r0 * (gs[3][o0] + b_hn0));
            hc0 = (1.f - z0) * n0 + z0 * hc0;
            float r1 = sigf(gs[0][o1] + b_r1);
            float z1 = sigf(gs[1][o1] + b_z1);
            float n1 = ftanh(gs[2][o1] + b_in1 + r1 * (gs[3][o1] + b_hn1));
            hc1 = (1.f - z1) * n1 + z1 * hc1;
            unsigned pkd = (unsigned)f2bf(hc0) | ((unsigned)f2bf(hc1) << 16);
            st_h32((char*)hout + ((size_t)(b0 + bA) * 512 + j0) * 2, pkd);
        }
        if (t == 255) {
            float2 hv = {hc0, hc1};
            *(float2*)&hidden[(size_t)(b0 + bA) * 1024 + dir * 512 + j0] = hv;
        } else {
            // prefetch x for t+1 into As x-region
            int tt2 = dir ? (254 - t) : (t + 1);
            const ushort* xr2 = xb16 + (size_t)tt2 * (B_ * 160);
            for (int i2 = 0; i2 < 3; ++i2) {
                int c = tid + i2 * 256;
                if (c < 640) {
                    int row = c / 20, off2 = c - row * 20;
                    ulonglong2 v = *(const ulonglong2*)(xr2 + (size_t)(b0 + row) * 160 + off2 * 8);
                    char* d = (char*)As + row * (ERS * 2) + off2 * 16;
                    *(u64*)d = v.x; *(u64*)(d + 8) = v.y;
                }
            }
        }
        __syncthreads();                 // C: x(t+1) staged before next x-MFMA
    }
}

// =============== decoder step 1 (one-shot, 1 wave/block) ===============
__global__ __launch_bounds__(64, 1) void dec_step1(
    const ushort* __restrict__ hdec0, const ushort* __restrict__ WD1,
    const float* __restrict__ h0f, const float* __restrict__ gi0,
    const float* __restrict__ bhh, ushort* __restrict__ hist0,
    float* __restrict__ h1f)
{
    int bid = blockIdx.x;
    int rt = bid >> 5, cb = bid & 31;
    int lane = threadIdx.x;
    int m = lane & 15, kb = lane >> 4;
    int arow = rt * 16 + m;
    int j = cb * 16 + m;
    int orow = rt * 16 + kb * 4;
    const ushort* hr = hdec0 + (size_t)arow * 512 + kb * 8;
    bf16x8 af[16];
    #pragma unroll
    for (int ks = 0; ks < 16; ++ks)
        af[ks] = *(const bf16x8*)(hr + ks * 32);
    const ushort* w1 = WD1 + (size_t)(cb * 64) * 512 + lane * 8;
    f32x4 aR = {0.f,0.f,0.f,0.f}, aZ = {0.f,0.f,0.f,0.f}, aGh = {0.f,0.f,0.f,0.f};
    #pragma unroll
    for (int ks = 0; ks < 16; ++ks) {
        aR = MFMA16(af[ks], *(const bf16x8*)(w1 + (size_t)ks * 512), aR);
        aZ = MFMA16(af[ks], *(const bf16x8*)(w1 + (size_t)(16 + ks) * 512), aZ);
        aGh = MFMA16(af[ks], *(const bf16x8*)(w1 + (size_t)(48 + ks) * 512), aGh);
    }
    float bh_r = bhh[j], bh_z = bhh[512 + j], bh_n = bhh[1024 + j];
    #pragma unroll
    for (int i = 0; i < 4; ++i) {
        int rg = orow + i;
        float gr = gi0[(size_t)rg * G3_ + j];
        float gz = gi0[(size_t)rg * G3_ + 512 + j];
        float gn = gi0[(size_t)rg * G3_ + 1024 + j];
        float h0 = h0f[(size_t)rg * 512 + j];
        float r = sigf(aR[i] + gr + bh_r);
        float z = sigf(aZ[i] + gz + bh_z);
        float n = ftanh(gn + r * (aGh[i] + bh_n));
        float h1 = (1.f - z) * n + z * h0;
        h1f[(size_t)rg * 512 + j] = h1;
        hist0[(size_t)rg * 512 + j] = f2bf(h1);
    }
}

// =============== persistent decoder (t = 2..255) ===============
// grid 128 = bt(4) x cb(32); block 256 = 4 waves. LDS weights; batched retry.
__global__ __launch_bounds__(256) void dec_persist(
    const ushort* __restrict__ WD2, ushort* __restrict__ hist,  // [255][128][512]
    const float* __restrict__ h1f, const float* __restrict__ bfi,
    const float* __restrict__ bhh)
{
    __shared__ ushort As[32 * DRS];      // 33.5 KB
    __shared__ ushort Ws[64 * 512];      // 64 KB
    __shared__ float gs[4][512];         // 8 KB
    int bid = blockIdx.x;
    int bt = bid >> 5, cb = bid & 31;
    int b0 = bt * 32, tid = threadIdx.x;
    {
        const ushort* src = WD2 + (size_t)(cb * 64) * 512;
        for (int c = tid; c < 4096; c += 256)
            *(uint4*)&Ws[c * 8] = *(const uint4*)&src[c * 8];
    }
    int bA = tid >> 3;
    int j0 = cb * 16 + 2 * (tid & 7), j1 = j0 + 1;
    float f_r0 = bfi[j0] + bhh[j0],             f_r1 = bfi[j1] + bhh[j1];
    float f_z0 = bfi[512 + j0] + bhh[512 + j0], f_z1 = bfi[512 + j1] + bhh[512 + j1];
    float f_in0 = bfi[1024 + j0],               f_in1 = bfi[1024 + j1];
    float f_hn0 = bhh[1024 + j0],               f_hn1 = bhh[1024 + j1];
    float hc0 = h1f[(size_t)(b0 + bA) * 512 + j0];
    float hc1 = h1f[(size_t)(b0 + bA) * 512 + j1];

    int lane = tid & 63, wv = tid >> 6;
    int m = lane & 15, kb = lane >> 4;
    int ai0 = m * DRS + kb * 8, ai1 = (16 + m) * DRS + kb * 8;

    for (int t = 2; t < T_; ++t) {
        const ushort* hin = hist + (size_t)(t - 2) * 65536;
        u64 vb[16];
        for (;;) {
            #pragma unroll
            for (int i = 0; i < 16; ++i) {
                int c = tid + i * 256;
                int row = c >> 7, off = c & 127;
                vb[i] = ld_h64(hin + (size_t)(b0 + row) * 512 + off * 4);
            }
            u64 bad = 0;
            #pragma unroll
            for (int i = 0; i < 16; ++i) bad |= badm(vb[i]);
            if (__all(bad == 0)) break;
        }
        #pragma unroll
        for (int i = 0; i < 16; ++i) {
            int c = tid + i * 256;
            int row = c >> 7, off = c & 127;
            *(u64*)((char*)As + row * (DRS * 2) + off * 8) = vb[i];
        }
        __syncthreads();
        f32x4 acc0 = {0.f,0.f,0.f,0.f}, acc1 = {0.f,0.f,0.f,0.f};
        const ushort* Bp = &Ws[(wv * 16) * 512 + lane * 8];
        for (int ks = 0; ks < 16; ++ks) {
            bf16x8 bfr = *(const bf16x8*)(Bp + (size_t)ks * 512);
            bf16x8 a0 = lds_frag(&As[ai0 + ks * 32]);
            bf16x8 a1 = lds_frag(&As[ai1 + ks * 32]);
            acc0 = MFMA16(a0, bfr, acc0);
            acc1 = MFMA16(a1, bfr, acc1);
        }
        #pragma unroll
        for (int i = 0; i < 4; ++i) {
            gs[wv][(kb * 4 + i) * 16 + m] = acc0[i];
            gs[wv][(16 + kb * 4 + i) * 16 + m] = acc1[i];
        }
        __syncthreads();
        {
            int o0 = 2 * tid, o1 = o0 + 1;
            float r0 = sigf(gs[0][o0] + f_r0);
            float z0 = sigf(gs[1][o0] + f_z0);
            float n0 = ftanh(gs[2][o0] + f_in0 + r0 * (gs[3][o0] + f_hn0));
            hc0 = (1.f - z0) * n0 + z0 * hc0;
            float r1 = sigf(gs[0][o1] + f_r1);
            float z1 = sigf(gs[1][o1] + f_z1);
            float n1 = ftanh(gs[2][o1] + f_in1 + r1 * (gs[3][o1] + f_hn1));
            hc1 = (1.f - z1) * n1 + z1 * hc1;
            unsigned pkd = (unsigned)f2bf(hc0) | ((unsigned)f2bf(hc1) << 16);
            st_h32((char*)(hist + (size_t)(t - 1) * 65536) +
                   ((size_t)(b0 + bA) * 512 + j0) * 2, pkd);
        }
    }
}

// =============== notes GEMM (MFMA): hist @ Wdec1.T + b -> out[:,1:,:] ===============
__global__ __launch_bounds__(256) void notes_mfma(
    const ushort* __restrict__ hist, const ushort* __restrict__ pk,
    const float* __restrict__ bd, float* __restrict__ out)
{
    __shared__ ushort hs[32 * DRS];
    int m0 = blockIdx.x * 32;
    int tid = threadIdx.x;
    #pragma unroll
    for (int i = 0; i < 8; ++i) {
        int c = tid + i * 256;
        int row = c >> 6, off = c & 63;
        ulonglong2 v = *(const ulonglong2*)(hist + (size_t)(m0 + row) * 512 + off * 8);
        char* d = (char*)hs + row * (DRS * 2) + off * 16;
        *(u64*)d = v.x; *(u64*)(d + 8) = v.y;
    }
    __syncthreads();
    int lane = tid & 63, wv = tid >> 6;
    int m = lane & 15, kb = lane >> 4;
    int nt0 = wv * 2;
    f32x4 acc00 = {0.f,0.f,0.f,0.f}, acc01 = {0.f,0.f,0.f,0.f};
    f32x4 acc10 = {0.f,0.f,0.f,0.f}, acc11 = {0.f,0.f,0.f,0.f};
    for (int ks = 0; ks < 16; ++ks) {
        bf16x8 a0 = lds_frag(&hs[m * DRS + ks * 32 + kb * 8]);
        bf16x8 a1 = lds_frag(&hs[(16 + m) * DRS + ks * 32 + kb * 8]);
        bf16x8 bf0 = *(const bf16x8*)&pk[(size_t)((nt0 * 16 + ks) * 64 + lane) * 8];
        bf16x8 bf1 = *(const bf16x8*)&pk[(size_t)(((nt0 + 1) * 16 + ks) * 64 + lane) * 8];
        acc00 = MFMA16(a0, bf0, acc00);
        acc01 = MFMA16(a0, bf1, acc01);
        acc10 = MFMA16(a1, bf0, acc10);
        acc11 = MFMA16(a1, bf1, acc11);
    }
    int n0 = nt0 * 16 + (lane & 15), n1 = (nt0 + 1) * 16 + (lane & 15);
    #pragma unroll
    for (int i = 0; i < 4; ++i) {
        int r0 = m0 + kb * 4 + i;
        int r1 = r0 + 16;
        int t0 = r0 >> 7, b0r = r0 & 127;
        int t1 = r1 >> 7, b1r = r1 & 127;
        out[((size_t)b0r * T_ + (t0 + 1)) * IN_ + n0] = acc00[i] + bd[n0];
        out[((size_t)b0r * T_ + (t0 + 1)) * IN_ + n1] = acc01[i] + bd[n1];
        out[((size_t)b1r * T_ + (t1 + 1)) * IN_ + n0] = acc10[i] + bd[n0];
        out[((size_t)b1r * T_ + (t1 + 1)) * IN_ + n1] = acc11[i] + bd[n1];
    }
}

// =============== MLP GEMM (fp32 A, bf16 tiled W) ===============
__global__ __launch_bounds__(256) void gemm_t4(
    const float* __restrict__ A, const ushort4* __restrict__ Wt,
    const float* __restrict__ bias, float* __restrict__ C,
    int M, int N, int K, int act)
{
    int nb = blockIdx.x, mb = blockIdx.y;
    int tid = threadIdx.x;
    int n = nb * 64 + (tid & 63);
    int mq = tid >> 6;
    int m0 = mb * 32;
    __shared__ float Asm[32][36];
    float acc[8];
    #pragma unroll
    for (int i = 0; i < 8; ++i) acc[i] = 0.f;
    for (int k0 = 0; k0 < K; k0 += 32) {
        int r = tid >> 3, c = (tid & 7) << 2;
        float4 v = *(const float4*)&A[(size_t)(m0 + r) * K + k0 + c];
        Asm[r][c] = v.x; Asm[r][c+1] = v.y; Asm[r][c+2] = v.z; Asm[r][c+3] = v.w;
        __syncthreads();
        #pragma unroll
        for (int kc = 0; kc < 8; ++kc) {
            float w0 = 0.f, w1 = 0.f, w2 = 0.f, w3 = 0.f;
            if (n < N) {
                ushort4 u = Wt[(size_t)((k0 >> 2) + kc) * N + n];
                w0 = bf2f(u.x); w1 = bf2f(u.y); w2 = bf2f(u.z); w3 = bf2f(u.w);
            }
            #pragma unroll
            for (int i = 0; i < 8; ++i) {
                int mm = mq * 8 + i;
                acc[i] += Asm[mm][kc*4+0]*w0 + Asm[mm][kc*4+1]*w1
                        + Asm[mm][kc*4+2]*w2 + Asm[mm][kc*4+3]*w3;
            }
        }
        __syncthreads();
    }
    if (n < N) {
        #pragma unroll
        for (int i = 0; i < 8; ++i) {
            int mm = m0 + mq * 8 + i;
            float v = acc[i] + bias[n];
            if (act == 1) v = (v >= 0.f) ? v : 0.01f * v;
            C[(size_t)mm * N + n] = v;
        }
    }
}

__global__ void z_k(const float* __restrict__ out, const float* __restrict__ eps,
                    const float* __restrict__ genre, float* __restrict__ zc) {
    int id = blockIdx.x * 256 + threadIdx.x;
    if (id >= B_ * L_) return;
    int b = id >> 8, c = id & 255;
    float v;
    if (c < LG_) {
        float mu = out[MU_OFF + (size_t)b * LG_ + c];
        float lv = out[LV_OFF + (size_t)b * LG_ + c];
        v = mu + expf(0.5f * lv) * eps[(size_t)b * LG_ + c];
    } else {
        v = genre[(size_t)b * G_ + (c - LG_)];
    }
    zc[id] = v;
}

// =============== host ===============
extern "C" void kernel_launch(void* const* d_in, const int* in_sizes, int n_in,
                              void* d_out, int out_size, void* d_ws, size_t ws_size,
                              hipStream_t stream) {
    (void)in_sizes; (void)n_in; (void)out_size; (void)ws_size;
    const float* x      = (const float*)d_in[0];
    const float* genre  = (const float*)d_in[1];
    const float* eps    = (const float*)d_in[2];
    const float* Wih_e  = (const float*)d_in[3];
    const float* Whh_e  = (const float*)d_in[4];
    const float* bih_e  = (const float*)d_in[5];
    const float* bhh_e  = (const float*)d_in[6];
    const float* Wih_be = (const float*)d_in[7];
    const float* Whh_be = (const float*)d_in[8];
    const float* bih_be = (const float*)d_in[9];
    const float* bhh_be = (const float*)d_in[10];
    const float* Wih_d  = (const float*)d_in[11];
    const float* Whh_d  = (const float*)d_in[12];
    const float* bih_d  = (const float*)d_in[13];
    const float* bhh_d  = (const float*)d_in[14];
    const float* W_mu0  = (const float*)d_in[15];
    const float* b_mu0  = (const float*)d_in[16];
    const float* W_mu1  = (const float*)d_in[17];
    const float* b_mu1  = (const float*)d_in[18];
    const float* W_lv0  = (const float*)d_in[19];
    const float* b_lv0  = (const float*)d_in[20];
    const float* W_lv1  = (const float*)d_in[21];
    const float* b_lv1  = (const float*)d_in[22];
    const float* W_lat0 = (const float*)d_in[23];
    const float* b_lat0 = (const float*)d_in[24];
    const float* W_lat1 = (const float*)d_in[25];
    const float* b_lat1 = (const float*)d_in[26];
    const float* W_dec1 = (const float*)d_in[27];
    const float* b_dec1 = (const float*)d_in[28];
    float* out = (float*)d_out;

    char* ws = (char*)d_ws;
    size_t off = 0;
    auto alloc = [&](size_t bytes) -> char* {
        char* p = ws + off;
        off = (off + bytes + 255) & ~(size_t)255;
        return p;
    };
    ushort* xb16  = (ushort*)alloc((size_t)T_ * B_ * 160 * 2);
    ushort* WE    = (ushort*)alloc((size_t)2 * 32 * 63 * 512 * 2);
    ushort* WD2   = (ushort*)alloc((size_t)32 * 64 * 512 * 2);
    ushort* WD1   = (ushort*)alloc((size_t)32 * 64 * 512 * 2);
    float*  Wf    = (float*)alloc((size_t)G3_ * H_ * 4);
    float*  bfi   = (float*)alloc(G3_ * 4);
    ushort* hb_e  = (ushort*)alloc((size_t)256 * 2 * 65536 * 2);   // 67 MB
    ushort* hist  = (ushort*)alloc((size_t)255 * 65536 * 2);       // 33 MB
    ushort* hdec0 = (ushort*)alloc((size_t)65536 * 2);
    ushort* pkdec = (ushort*)alloc((size_t)8192 * 8 * 2);
    float*  note0f= (float*)alloc((size_t)B_ * 128 * 4);
    float*  gi0   = (float*)alloc((size_t)B_ * G3_ * 4);
    float*  hidden= (float*)alloc((size_t)B_ * E_ * 4);
    float*  t0buf = (float*)alloc((size_t)B_ * E_ * 4);
    float*  t1buf = (float*)alloc((size_t)B_ * E_ * 4);
    float*  zcbuf = (float*)alloc((size_t)B_ * L_ * 4);
    float*  t2buf = (float*)alloc((size_t)B_ * L_ * 4);
    float*  t3buf = (float*)alloc((size_t)B_ * H_ * 4);
    float*  h1f   = (float*)alloc((size_t)B_ * H_ * 4);

    ushort4* T_Wmu0  = (ushort4*)alloc((size_t)256 * E_ * 8);
    ushort4* T_Wmu1  = (ushort4*)alloc((size_t)256 * LG_ * 8);
    ushort4* T_Wlv0  = (ushort4*)alloc((size_t)256 * E_ * 8);
    ushort4* T_Wlv1  = (ushort4*)alloc((size_t)256 * LG_ * 8);
    ushort4* T_Wlat0 = (ushort4*)alloc((size_t)64 * L_ * 8);
    ushort4* T_Wlat1 = (ushort4*)alloc((size_t)64 * H_ * 8);
    ushort4* T_Wihd  = (ushort4*)alloc((size_t)32 * G3_ * 8);

    // ---- prep ----
    xpad_k<<<(T_ * B_ * 160 + 255) / 256, 256, 0, stream>>>(x, xb16);
    pack_we<<<1008, 256, 0, stream>>>(Wih_e, Whh_e, Wih_be, Whh_be, WE);
    wfused_k<<<(G3_ * H_ + 255) / 256, 256, 0, stream>>>(Wih_d, W_dec1, Wf);
    bfi_k<<<6, 256, 0, stream>>>(Wih_d, b_dec1, bih_d, bfi);
    pack_wd<<<512, 256, 0, stream>>>(Wf, Whh_d, WD2, 1);
    pack_wd<<<512, 256, 0, stream>>>(Wf, Whh_d, WD1, 0);
    pack_wdec<<<32, 256, 0, stream>>>(W_dec1, pkdec);
    poison_k<<<16384, 256, 0, stream>>>((ulonglong2*)hb_e, (ulonglong2*)hist);
    note0_k2<<<(B_ * IN_ + 255) / 256, 256, 0, stream>>>(x, out, note0f);

    auto tile = [&](const float* W, ushort4* dst, int N, int K) {
        int KC = (K + 3) / 4;
        tile_w<<<(KC * N + 255) / 256, 256, 0, stream>>>(W, dst, N, K, KC);
    };
    tile(W_mu0,  T_Wmu0,  E_,  E_);
    tile(W_mu1,  T_Wmu1,  LG_, E_);
    tile(W_lv0,  T_Wlv0,  E_,  E_);
    tile(W_lv1,  T_Wlv1,  LG_, E_);
    tile(W_lat0, T_Wlat0, L_,  L_);
    tile(W_lat1, T_Wlat1, H_,  L_);
    tile(Wih_d,  T_Wihd,  G3_, IN_);

    // ---- persistent bidirectional encoder (data-as-flag, LDS weights) ----
    enc_persist<<<256, 256, 0, stream>>>(xb16, WE, hb_e, hidden,
                                         bih_e, bhh_e, bih_be, bhh_be);

    // ---- MLP bottleneck ----
    {
        dim3 g1(16, 4), g2(4, 4), g3(4, 4), g4(8, 4), g5(24, 4);
        gemm_t4<<<g1, 256, 0, stream>>>(hidden, T_Wmu0, b_mu0, t0buf, B_, E_, E_, 1);
        gemm_t4<<<g2, 256, 0, stream>>>(t0buf, T_Wmu1, b_mu1, out + MU_OFF, B_, LG_, E_, 0);
        gemm_t4<<<g1, 256, 0, stream>>>(hidden, T_Wlv0, b_lv0, t1buf, B_, E_, E_, 1);
        gemm_t4<<<g2, 256, 0, stream>>>(t1buf, T_Wlv1, b_lv1, out + LV_OFF, B_, LG_, E_, 0);
        z_k<<<(B_ * L_ + 255) / 256, 256, 0, stream>>>(out, eps, genre, zcbuf);
        gemm_t4<<<g3, 256, 0, stream>>>(zcbuf, T_Wlat0, b_lat0, t2buf, B_, L_, L_, 1);
        gemm_t4<<<g4, 256, 0, stream>>>(t2buf, T_Wlat1, b_lat1, t3buf, B_, H_, L_, 0);
        gemm_t4<<<g5, 256, 0, stream>>>(note0f, T_Wihd, bih_d, gi0, B_, G3_, IN_, 0);
    }
    cvt_h0<<<(B_ * H_ + 255) / 256, 256, 0, stream>>>(t3buf, hdec0);

    // ---- decoder step 1 + persistent decoder (t=2..255, data-as-flag) ----
    dec_step1<<<256, 64, 0, stream>>>(hdec0, WD1, t3buf, gi0, bhh_d, hist, h1f);
    dec_persist<<<128, 256, 0, stream>>>(WD2, hist, h1f, bfi, bhh_d);

    // ---- all notes (MFMA GEMM) ----
    notes_mfma<<<1020, 256, 0, stream>>>(hist, pkdec, b_dec1, out);
}